// Round 9
// baseline (261.636 us; speedup 1.0000x reference)
//
#include <hip/hip_runtime.h>
#include <hip/hip_fp16.h>
#include <math.h>

#define BB   16
#define SS   1024
#define PP   1024
#define HH   8
#define MSS  32
#define EE   524288
#define NROW (BB*SS)   /* 16384 */
#define NCOL (BB*PP)   /* 16384 */
#define ESTRIDE 5      /* dwords per edge entry: [0]=other id, [1..4]=8 x fp16 ev */
#define NRWB 512       /* row-blocks per XCD slot: 512 blocks x 4 waves = 2048 rows */
#define NB   128       /* hist/pos blocks */
#define CHUNK 4096     /* edges per hist/pos block */
#define GCAP 96        /* staged entries per group in combine (fallback past this) */

// async global->LDS, 16B per lane. LDS dest is wave-uniform base + lane*16,
// which matches our linear idx = li*256 + t layout exactly (m104/m108).
#define GLL(gp, lp) __builtin_amdgcn_global_load_lds( \
    (const __attribute__((address_space(1))) void*)(gp), \
    (__attribute__((address_space(3))) void*)(lp), 16, 0, 0)

// ---------------- projection (merged-ct GEMM, gll-dbuf) ---------------------
// BK=16 double-buffered B staging via global_load_lds (zero staging VGPRs;
// round-6's reg-prefetch spilled). Issue kc+1 loads before kc's compute; the
// per-kc __syncthreads drains vmcnt ~2048cy later, so L2 latency hides under
// compute. Accumulation order unchanged -> bit-identical outputs.
__global__ __launch_bounds__(256, 2) void proj_kernel(
        const float* __restrict__ x1, const float* __restrict__ x2,
        const float* __restrict__ Wqv1, const float* __restrict__ Wkv2,
        float* __restrict__ qf, float* __restrict__ kf,
        __half* __restrict__ v1h, __half* __restrict__ v2h) {
    __shared__ float As[64 * 132];
    __shared__ float Bs[2][16 * 256];
    int t = threadIdx.x;
    int bid = blockIdx.x;
    int matrix = bid >> 8;          // 0: x1@Wqv1, 1: x2@Wkv2
    int mb = bid & 255;
    const float* A  = matrix ? x2 : x1;
    const float* Bm = matrix ? Wkv2 : Wqv1;
    const float* Arow = A + (size_t)mb * 64 * 128;

    int tx = t & 31, ty = t >> 5;
    // stage A-tile (64 x 128) once
#pragma unroll
    for (int li = 0; li < 8; li++) {
        int idx = li * 256 + t;
        int r = idx >> 5, p = idx & 31;
        *(float4*)&As[r * 132 + 4 * p] = *(const float4*)(Arow + r * 128 + 4 * p);
    }
    // issue B(kc=0): 16 rows x 256 cols = 1024 float4, 4 per thread, contiguous
#pragma unroll
    for (int li = 0; li < 4; li++) {
        int idx = li * 256 + t;
        GLL(Bm + 4 * idx, &Bs[0][4 * idx]);
    }

    float4 accL[8], accR[8];
#pragma unroll
    for (int i = 0; i < 8; i++) {
        accL[i] = make_float4(0.f, 0.f, 0.f, 0.f);
        accR[i] = make_float4(0.f, 0.f, 0.f, 0.f);
    }

    __syncthreads();   // drains vmcnt (B0 in LDS) + lgkm (As) + barrier

    for (int kc = 0; kc < 8; kc++) {
        if (kc < 7) {   // issue next B tile -> latency hides under this kc's compute
            const float* src = Bm + (size_t)(kc + 1) * 16 * 256;
            float* dst = Bs[(kc + 1) & 1];
#pragma unroll
            for (int li = 0; li < 4; li++) {
                int idx = li * 256 + t;
                GLL(src + 4 * idx, dst + 4 * idx);
            }
        }
        const float* Bcur = Bs[kc & 1];
#pragma unroll
        for (int kq = 0; kq < 4; kq++) {
            float4 a4[8];
#pragma unroll
            for (int i = 0; i < 8; i++)
                a4[i] = *(const float4*)&As[(ty + 8 * i) * 132 + kc * 16 + kq * 4];
#pragma unroll
            for (int kk = 0; kk < 4; kk++) {
                float4 bL = *(const float4*)&Bcur[(kq * 4 + kk) * 256 + 4 * tx];
                float4 bR = *(const float4*)&Bcur[(kq * 4 + kk) * 256 + 128 + 4 * tx];
#pragma unroll
                for (int i = 0; i < 8; i++) {
                    float av = ((const float*)&a4[i])[kk];
                    accL[i].x = fmaf(av, bL.x, accL[i].x);
                    accL[i].y = fmaf(av, bL.y, accL[i].y);
                    accL[i].z = fmaf(av, bL.z, accL[i].z);
                    accL[i].w = fmaf(av, bL.w, accL[i].w);
                    accR[i].x = fmaf(av, bR.x, accR[i].x);
                    accR[i].y = fmaf(av, bR.y, accR[i].y);
                    accR[i].z = fmaf(av, bR.z, accR[i].z);
                    accR[i].w = fmaf(av, bR.w, accR[i].w);
                }
            }
        }
        __syncthreads();   // readers of Bs[kc&1] done; drains kc+1 loads (complete)
    }

    float* Cq = matrix ? kf : qf;
    __half* Cv = matrix ? v2h : v1h;
#pragma unroll
    for (int i = 0; i < 8; i++) {
        int row = mb * 64 + ty + 8 * i;
        *(float4*)(Cq + (size_t)row * 128 + 4 * tx) = accL[i];
        __half2* p = (__half2*)(Cv + (size_t)row * 128 + 4 * tx);
        p[0] = __halves2half2(__float2half(accR[i].x), __float2half(accR[i].y));
        p[1] = __halves2half2(__float2half(accR[i].z), __float2half(accR[i].w));
    }
}

// ---------------- output GEMMs (gll-dbuf, N=128) ----------------------------
__global__ __launch_bounds__(256) void outp_kernel(
        const float* __restrict__ rh, const float* __restrict__ ch,
        const float* __restrict__ Wo1, const float* __restrict__ Wo2,
        float* __restrict__ out) {
    __shared__ float As[64 * 132];
    __shared__ float Bs[2][16 * 128];
    int t = threadIdx.x;
    int matrix = blockIdx.x >> 8;
    int mb = blockIdx.x & 255;
    const float* A  = matrix ? ch : rh;
    const float* Bm = matrix ? Wo2 : Wo1;
    float* C = out + (size_t)matrix * NROW * 128;
    const float* Arow = A + (size_t)mb * 64 * 128;

    int tx = t & 31, ty = t >> 5;
#pragma unroll
    for (int li = 0; li < 8; li++) {
        int idx = li * 256 + t;
        int r = idx >> 5, p = idx & 31;
        *(float4*)&As[r * 132 + 4 * p] = *(const float4*)(Arow + r * 128 + 4 * p);
    }
    // issue B(kc=0): 16 x 128 = 512 float4, 2 per thread, contiguous
#pragma unroll
    for (int li = 0; li < 2; li++) {
        int idx = li * 256 + t;
        GLL(Bm + 4 * idx, &Bs[0][4 * idx]);
    }

    float4 acc4[8];
#pragma unroll
    for (int i = 0; i < 8; i++) acc4[i] = make_float4(0.f, 0.f, 0.f, 0.f);

    __syncthreads();

    for (int kc = 0; kc < 8; kc++) {
        if (kc < 7) {
            const float* src = Bm + (size_t)(kc + 1) * 16 * 128;
            float* dst = Bs[(kc + 1) & 1];
#pragma unroll
            for (int li = 0; li < 2; li++) {
                int idx = li * 256 + t;
                GLL(src + 4 * idx, dst + 4 * idx);
            }
        }
        const float* Bcur = Bs[kc & 1];
#pragma unroll
        for (int kq = 0; kq < 4; kq++) {
            float4 a4[8];
#pragma unroll
            for (int i = 0; i < 8; i++)
                a4[i] = *(const float4*)&As[(ty + 8 * i) * 132 + kc * 16 + kq * 4];
#pragma unroll
            for (int kk = 0; kk < 4; kk++) {
                float4 b4 = *(const float4*)&Bcur[(kq * 4 + kk) * 128 + 4 * tx];
#pragma unroll
                for (int i = 0; i < 8; i++) {
                    float av = ((const float*)&a4[i])[kk];
                    acc4[i].x = fmaf(av, b4.x, acc4[i].x);
                    acc4[i].y = fmaf(av, b4.y, acc4[i].y);
                    acc4[i].z = fmaf(av, b4.z, acc4[i].z);
                    acc4[i].w = fmaf(av, b4.w, acc4[i].w);
                }
            }
        }
        __syncthreads();
    }

#pragma unroll
    for (int i = 0; i < 8; i++) {
        int row = mb * 64 + ty + 8 * i;
        *(float4*)(C + (size_t)row * 128 + 4 * tx) = acc4[i];
    }
}

// ---------------- atomic-free histogram: per-block LDS, u16-packed ----------
__global__ __launch_bounds__(1024) void hist_kernel(
        const int* __restrict__ b_idx, const int* __restrict__ s_idx,
        const int* __restrict__ p_idx, unsigned int* __restrict__ ph) {
    __shared__ unsigned int lh[16384];
    int t = threadIdx.x;
#pragma unroll
    for (int i = 0; i < 16; i++) lh[t + 1024 * i] = 0;
    __syncthreads();
    int base = blockIdx.x * CHUNK;
#pragma unroll
    for (int k = 0; k < 4; k++) {
        int e = base + k * 1024 + t;
        int b = b_idx[e];
        int rbin = (b << 10) + s_idx[e];
        int cbin = 16384 + (b << 10) + p_idx[e];
        atomicAdd(&lh[rbin >> 1], 1u << (16 * (rbin & 1)));
        atomicAdd(&lh[cbin >> 1], 1u << (16 * (cbin & 1)));
    }
    __syncthreads();
    unsigned int* dst = ph + (size_t)blockIdx.x * 16384;
#pragma unroll
    for (int i = 0; i < 16; i++) dst[t + 1024 * i] = lh[t + 1024 * i];
}

// ---- scan1: per-bin serial prefix over the 128 block-partials --------------
__global__ __launch_bounds__(128) void scan1_kernel(
        const unsigned int* __restrict__ ph, int* __restrict__ pbase,
        int* __restrict__ tot) {
    int bin = blockIdx.x * 128 + threadIdx.x;   // 0..32767
    int word = bin >> 1;
    int sh = 16 * (bin & 1);
    int run = 0;
#pragma unroll 8
    for (int j = 0; j < NB; j++) {
        unsigned int v = ph[(size_t)j * 16384 + word];
        pbase[(size_t)j * 32768 + bin] = run;
        run += (v >> sh) & 0xffff;
    }
    tot[bin] = run;
}

// ---- scan2: exclusive scan of 16384 bin totals per side -> offs ------------
__global__ __launch_bounds__(1024) void scan2_kernel(
        const int* __restrict__ tot, int* __restrict__ offs) {
    __shared__ int sdata[1024];
    int side = blockIdx.x;
    int t = threadIdx.x;
    const int* c = tot + side * 16384;
    int* o = offs + side * (16384 + 1);
    int base = t * 16;
    int loc[16];
    int run = 0;
#pragma unroll
    for (int i = 0; i < 16; i++) { loc[i] = run; run += c[base + i]; }
    sdata[t] = run;
    __syncthreads();
    for (int st = 1; st < 1024; st <<= 1) {
        int v = (t >= st) ? sdata[t - st] : 0;
        __syncthreads();
        sdata[t] += v;
        __syncthreads();
    }
    int excl = sdata[t] - run;
#pragma unroll
    for (int i = 0; i < 16; i++) o[base + i] = excl + loc[i];
    if (t == 1023) o[16384] = sdata[1023];
}

// ---- pos: merged col+row positioning (posC+posR of round 9) ----------------
__global__ __launch_bounds__(1024) void pos_kernel(
        const int* __restrict__ b_idx, const int* __restrict__ s_idx,
        const int* __restrict__ p_idx, const float* __restrict__ w,
        const int* __restrict__ pbase, const int* __restrict__ offs,
        int4* __restrict__ ebuf) {
    __shared__ int cur[16384];
    int t = threadIdx.x;
    // phase 1: col cursors
    {
        const int* src = pbase + (size_t)blockIdx.x * 32768 + 16384;
        const int* oc = offs + (16384 + 1);
#pragma unroll
        for (int i = 0; i < 16; i++) {
            int idx = t + 1024 * i;
            cur[idx] = oc[idx] + src[idx];
        }
    }
    __syncthreads();
    int base = blockIdx.x * CHUNK;
    int rowr[4], colr[4], pcr[4];
    float wr[4];
#pragma unroll
    for (int k = 0; k < 4; k++) {
        int e = base + k * 1024 + t;
        int b = b_idx[e];
        rowr[k] = (b << 10) + s_idx[e];
        colr[k] = (b << 10) + p_idx[e];
        wr[k] = w[e];
        pcr[k] = atomicAdd(&cur[colr[k]], 1);
    }
    __syncthreads();
    // phase 2: row cursors
    {
        const int* src = pbase + (size_t)blockIdx.x * 32768;
#pragma unroll
        for (int i = 0; i < 16; i++) {
            int idx = t + 1024 * i;
            cur[idx] = offs[idx] + src[idx];
        }
    }
    __syncthreads();
#pragma unroll
    for (int k = 0; k < 4; k++) {
        int pr = atomicAdd(&cur[rowr[k]], 1);
        ebuf[pr] = make_int4(rowr[k], colr[k], __float_as_int(wr[k]), pcr[k]);
    }
}

// ---------------- fused edge pass (one wave per row, 2-deep pipelined) ------
// Round-15: the edge kernel is LATENCY-bound, not throughput-bound (r8 PMC:
// issue floor ~12us vs 44us measured; VALUBusy 54%; two chained L2/L3 round
// trips -- ebuf rec then k-row -- per 8-edge batch with only ~3 waves/SIMD
// covering them). Fix: software-pipeline the batch loop 2-deep. While batch b
// computes: k(b+1) already in regs (issued during b-1), rec(b+2) in flight,
// rec(b+3) issued before compute(b+1). MLP reverted to the wp[m] LDS
// broadcast path (bit-identical numerics to rounds 0-7; drops r8's shfl
// overhead + bank conflicts). VGPR ~40 -> ~76 (4 waves/SIMD cap = measured
// residency today, so no TLP loss).
__global__ __launch_bounds__(256) void edge_kernel(
        const float* __restrict__ qf, const float* __restrict__ kf,
        const int4* __restrict__ ebuf, const int* __restrict__ offs_row,
        const float* __restrict__ msW1, const float* __restrict__ msb1,
        const float* __restrict__ msW2, const float* __restrict__ msb2,
        float* __restrict__ entr, float* __restrict__ entc) {
    __shared__ float4 sPk[8 * 33];
    __shared__ float sB2[8];
    int t = threadIdx.x;
    {
        int h = t >> 5, m = t & 31;
        sPk[h * 33 + m] = make_float4(msW1[h * 64 + m], msW1[h * 64 + 32 + m],
                                      msb1[h * 32 + m], msW2[h * 32 + m]);
    }
    if (t < 8) sB2[t] = msb2[t];
    __syncthreads();

    int x = blockIdx.x & 7;          // XCD slot -> buckets x and x+8
    int ridx = blockIdx.x >> 3;      // 0..NRWB-1
    int wv = t >> 6;                 // wave in block (0..3)
    int lane = t & 63;
    int l = lane & 7;                // lane within 8-lane edge group
    int g = lane >> 3;               // edge group (0..7)

    int rl = ridx * 4 + wv;                                   // 0..2047
    int row = ((x + ((rl >> 10) << 3)) << 10) + (rl & 1023);  // global row id
    int s = offs_row[row];
    int cnt = offs_row[row + 1] - s;
    if (cnt <= 0) return;            // wave-uniform exit (after staging barrier)

    int hh = 2 * (l & 3) + (l >> 2);
    const float4* wp = &sPk[hh * 33];
    float bias2 = sB2[hh];

    // q-row fragments, loaded once per row
    const float4* qp4 = (const float4*)(qf + (size_t)row * 128);
    float4 q0 = qp4[l], q1 = qp4[8 + l], q2 = qp4[16 + l], q3 = qp4[24 + l];

    int nb = (cnt + 7) >> 3;
    auto posOf = [&](int b) {
        int j = b * 8 + g;
        if (j >= cnt) j = cnt - 1;
        return s + j;
    };

    auto compute = [&](int bb, int4 rec,
                       float4 k0, float4 k1, float4 k2, float4 k3) {
        int j = bb * 8 + g;
        bool valid = j < cnt;
        int pos = s + (valid ? j : cnt - 1);
        int col = rec.y;
        float we = __int_as_float(rec.z);
        int pc = rec.w;

        float p0 = fmaf(q0.x, k0.x, fmaf(q0.y, k0.y, fmaf(q0.z, k0.z, q0.w * k0.w)));
        float p1 = fmaf(q1.x, k1.x, fmaf(q1.y, k1.y, fmaf(q1.z, k1.z, q1.w * k1.w)));
        float p2 = fmaf(q2.x, k2.x, fmaf(q2.y, k2.y, fmaf(q2.z, k2.z, q2.w * k2.w)));
        float p3 = fmaf(q3.x, k3.x, fmaf(q3.y, k3.y, fmaf(q3.z, k3.z, q3.w * k3.w)));
        p0 += __shfl_xor(p0, 1); p0 += __shfl_xor(p0, 2);
        p1 += __shfl_xor(p1, 1); p1 += __shfl_xor(p1, 2);
        p2 += __shfl_xor(p2, 1); p2 += __shfl_xor(p2, 2);
        p3 += __shfl_xor(p3, 1); p3 += __shfl_xor(p3, 2);

        int js = l & 3;
        float dot = js == 0 ? p0 : (js == 1 ? p1 : (js == 2 ? p2 : p3));
        float logit = dot * 0.25f;

        float outv = bias2;
#pragma unroll 4
        for (int m = 0; m < MSS; m++) {
            float4 c = wp[m];
            float hid = fmaf(logit, c.x, fmaf(we, c.y, c.z));
            hid = fmaxf(hid, 0.f);
            outv = fmaf(hid, c.w, outv);
        }
        // fast tanh+exp: tanh(x) = 1 - 2/(e^{2x}+1); ev = e^{10*tanh}
        float u  = __expf(outv + outv);
        float th = 1.0f - 2.0f * __builtin_amdgcn_rcpf(u + 1.0f);
        float ev = __expf(10.0f * th);
        __half evh = __float2half(ev);

        if (valid) {
            float* er = entr + (size_t)pos * ESTRIDE;
            float* ec = entc + (size_t)pc * ESTRIDE;
            ((__half*)er)[2 + hh] = evh;
            ((__half*)ec)[2 + hh] = evh;
            if (l == 0) {
                er[0] = __int_as_float(col);
                ec[0] = __int_as_float(row);
            }
        }
    };

    // ---- prologue: rec(0)+k(0), rec(1) in flight ----
    int4 recA = ebuf[posOf(0)];
    float4 a0, a1, a2, a3, b0, b1, b2, b3;
    {
        const float4* kp = (const float4*)(kf + (size_t)recA.y * 128);
        a0 = kp[l]; a1 = kp[8 + l]; a2 = kp[16 + l]; a3 = kp[24 + l];
    }
    int4 recB = recA, recC = recA, recD = recA;
    if (nb > 1) recB = ebuf[posOf(1)];

    for (int b = 0; b < nb; b += 2) {
        if (b + 1 < nb) {   // k(b+1): issued now, consumed after compute(b)
            const float4* kp = (const float4*)(kf + (size_t)recB.y * 128);
            b0 = kp[l]; b1 = kp[8 + l]; b2 = kp[16 + l]; b3 = kp[24 + l];
        }
        bool haveC = (b + 2 < nb);
        if (haveC) recC = ebuf[posOf(b + 2)];   // rec(b+2) in flight under compute(b)
        compute(b, recA, a0, a1, a2, a3);
        if (b + 1 >= nb) break;
        if (haveC) {        // k(b+2): issued now, consumed after compute(b+1)
            const float4* kp = (const float4*)(kf + (size_t)recC.y * 128);
            a0 = kp[l]; a1 = kp[8 + l]; a2 = kp[16 + l]; a3 = kp[24 + l];
        }
        bool haveD = (b + 3 < nb);
        if (haveD) recD = ebuf[posOf(b + 3)];   // rec(b+3) in flight under compute(b+1)
        compute(b + 1, recB, b0, b1, b2, b3);
        recA = recC;
        recB = haveD ? recD : recB;
    }
}

// ---------------- dual group-softmax combine (XCD-pinned, LDS-staged) -------
__global__ __launch_bounds__(128) void combine_kernel(
        const float* __restrict__ entr, const float* __restrict__ entc,
        const int* __restrict__ offs_row, const int* __restrict__ offs_col,
        const __half* __restrict__ v1h, const __half* __restrict__ v2h,
        float* __restrict__ row_heads, float* __restrict__ col_heads) {
    __shared__ float sE[GCAP * ESTRIDE];
    int x = blockIdx.x & 7;
    int r = blockIdx.x >> 3;
    int which = r >> 10;
    int sidx = r & 1023;
    int b = x + ((which & 1) << 3);
    int gl = (b << 10) + sidx;

    int t = threadIdx.x;
    int h = t >> 4;
    const float* ent; const __half* vals; const int* offs; float* outp;
    if (which < 2) { ent = entr; vals = v2h; offs = offs_row; outp = row_heads; }
    else           { ent = entc; vals = v1h; offs = offs_col; outp = col_heads; }
    int s = offs[gl], e_ = offs[gl + 1];
    int cnt = e_ - s;
    int cap = cnt < GCAP ? cnt : GCAP;

    const float* gsrc = ent + (size_t)s * ESTRIDE;
    for (int i = t; i < cap * ESTRIDE; i += 128) sE[i] = gsrc[i];
    __syncthreads();

    float acc = 0.f, den = 0.f;
#pragma unroll 8
    for (int i = 0; i < cap; i++) {
        const float* en = &sE[i * ESTRIDE];
        int other = __float_as_int(en[0]);
        float ev = __half2float(((const __half*)en)[2 + h]);
        float v = __half2float(vals[(size_t)other * 128 + t]);
        acc = fmaf(ev, v, acc);
        den += ev;
    }
    for (int i = cap; i < cnt; i++) {   // pathological-group fallback
        const float* en = gsrc + (size_t)i * ESTRIDE;
        int other = __float_as_int(en[0]);
        float ev = __half2float(((const __half*)en)[2 + h]);
        float v = __half2float(vals[(size_t)other * 128 + t]);
        acc = fmaf(ev, v, acc);
        den += ev;
    }
    outp[(size_t)gl * 128 + t] = acc / (den + 1e-9f);
}

extern "C" void kernel_launch(void* const* d_in, const int* in_sizes, int n_in,
                              void* d_out, int out_size, void* d_ws, size_t ws_size,
                              hipStream_t stream) {
    const float* x1   = (const float*)d_in[0];
    const float* x2   = (const float*)d_in[1];
    const int* b_idx  = (const int*)d_in[2];
    const int* s_idx  = (const int*)d_in[3];
    const int* p_idx  = (const int*)d_in[4];
    const float* w    = (const float*)d_in[5];
    const float* Wqv1 = (const float*)d_in[6];
    const float* Wkv2 = (const float*)d_in[7];
    const float* Wo1  = (const float*)d_in[8];
    const float* Wo2  = (const float*)d_in[9];
    const float* msW1 = (const float*)d_in[10];
    const float* msb1 = (const float*)d_in[11];
    const float* msW2 = (const float*)d_in[12];
    const float* msb2 = (const float*)d_in[13];
    float* out = (float*)d_out;

    // Workspace (~72 MiB) with aliased scratch (lifetimes disjoint):
    float* qf = (float*)d_ws;                         // 8.39 MB
    float* kf = qf + (size_t)NROW * 128;              // 8.39 MB
    __half* v1h = (__half*)(kf + (size_t)NCOL * 128); // 4.19 MB
    __half* v2h = v1h + (size_t)NROW * 128;           // 4.19 MB
    float* entr = (float*)(v2h + (size_t)NCOL * 128); // 10.49 MB
    float* entc = entr + (size_t)EE * ESTRIDE;        // 10.49 MB
    float* row_heads = entc + (size_t)EE * ESTRIDE;   // 8.39 MB
    float* col_heads = row_heads + (size_t)NROW * 128;// 8.39 MB
    int4* ebuf = (int4*)(col_heads + (size_t)NCOL * 128); // 8.39 MB
    int* offs = (int*)(ebuf + EE);                    // 2*(16384+1) ints
    int* tot  = offs + 2 * (16384 + 1);               // 32768 ints
    // aliases: ph -> entc (dead until edge); pbase -> heads (dead until combine).
    unsigned int* ph = (unsigned int*)entc;           // NB*16384 u32 = 8.39 MB
    int* pbase = (int*)row_heads;                     // NB*32768 int = 16.78 MB

    hist_kernel<<<NB, 1024, 0, stream>>>(b_idx, s_idx, p_idx, ph);
    scan1_kernel<<<256, 128, 0, stream>>>(ph, pbase, tot);
    scan2_kernel<<<2, 1024, 0, stream>>>(tot, offs);
    pos_kernel<<<NB, 1024, 0, stream>>>(b_idx, s_idx, p_idx, w, pbase, offs, ebuf);

    proj_kernel<<<512, 256, 0, stream>>>(x1, x2, Wqv1, Wkv2, qf, kf, v1h, v2h);

    edge_kernel<<<8 * NRWB, 256, 0, stream>>>(
        qf, kf, ebuf, offs, msW1, msb1, msW2, msb2, entr, entc);

    combine_kernel<<<2 * NROW, 128, 0, stream>>>(
        entr, entc, offs, offs + (16384 + 1), v1h, v2h, row_heads, col_heads);

    outp_kernel<<<512, 256, 0, stream>>>(row_heads, col_heads, Wo1, Wo2, out);
}

// Round 11
// 250.936 us; speedup vs baseline: 1.0426x; 1.0426x over previous
//
#include <hip/hip_runtime.h>
#include <hip/hip_fp16.h>
#include <math.h>

#define BB   16
#define SS   1024
#define PP   1024
#define HH   8
#define MSS  32
#define EE   524288
#define NROW (BB*SS)   /* 16384 */
#define NCOL (BB*PP)   /* 16384 */
#define ESTRIDE 5      /* dwords per edge entry: [0]=other id, [1..4]=8 x fp16 ev */
#define NRWB 512       /* row-blocks per XCD slot: 512 blocks x 4 waves = 2048 rows */
#define NB   128       /* hist/pos blocks */
#define CHUNK 4096     /* edges per hist/pos block */
#define GCAP 96        /* staged entries per group in combine (fallback past this) */

typedef __attribute__((ext_vector_type(2))) float v2f;

// async global->LDS, 16B per lane. LDS dest is wave-uniform base + lane*16,
// which matches our linear idx = li*256 + t layout exactly (m104/m108).
#define GLL(gp, lp) __builtin_amdgcn_global_load_lds( \
    (const __attribute__((address_space(1))) void*)(gp), \
    (__attribute__((address_space(3))) void*)(lp), 16, 0, 0)

// ---------------- projection (merged-ct GEMM, gll-dbuf) ---------------------
// BK=16 double-buffered B staging via global_load_lds (zero staging VGPRs;
// round-6's reg-prefetch spilled). Issue kc+1 loads before kc's compute; the
// per-kc __syncthreads drains vmcnt ~2048cy later, so L2 latency hides under
// compute. Accumulation order unchanged -> bit-identical outputs.
__global__ __launch_bounds__(256, 2) void proj_kernel(
        const float* __restrict__ x1, const float* __restrict__ x2,
        const float* __restrict__ Wqv1, const float* __restrict__ Wkv2,
        float* __restrict__ qf, float* __restrict__ kf,
        __half* __restrict__ v1h, __half* __restrict__ v2h) {
    __shared__ float As[64 * 132];
    __shared__ float Bs[2][16 * 256];
    int t = threadIdx.x;
    int bid = blockIdx.x;
    int matrix = bid >> 8;          // 0: x1@Wqv1, 1: x2@Wkv2
    int mb = bid & 255;
    const float* A  = matrix ? x2 : x1;
    const float* Bm = matrix ? Wkv2 : Wqv1;
    const float* Arow = A + (size_t)mb * 64 * 128;

    int tx = t & 31, ty = t >> 5;
    // stage A-tile (64 x 128) once
#pragma unroll
    for (int li = 0; li < 8; li++) {
        int idx = li * 256 + t;
        int r = idx >> 5, p = idx & 31;
        *(float4*)&As[r * 132 + 4 * p] = *(const float4*)(Arow + r * 128 + 4 * p);
    }
    // issue B(kc=0): 16 rows x 256 cols = 1024 float4, 4 per thread, contiguous
#pragma unroll
    for (int li = 0; li < 4; li++) {
        int idx = li * 256 + t;
        GLL(Bm + 4 * idx, &Bs[0][4 * idx]);
    }

    float4 accL[8], accR[8];
#pragma unroll
    for (int i = 0; i < 8; i++) {
        accL[i] = make_float4(0.f, 0.f, 0.f, 0.f);
        accR[i] = make_float4(0.f, 0.f, 0.f, 0.f);
    }

    __syncthreads();   // drains vmcnt (B0 in LDS) + lgkm (As) + barrier

    for (int kc = 0; kc < 8; kc++) {
        if (kc < 7) {   // issue next B tile -> latency hides under this kc's compute
            const float* src = Bm + (size_t)(kc + 1) * 16 * 256;
            float* dst = Bs[(kc + 1) & 1];
#pragma unroll
            for (int li = 0; li < 4; li++) {
                int idx = li * 256 + t;
                GLL(src + 4 * idx, dst + 4 * idx);
            }
        }
        const float* Bcur = Bs[kc & 1];
#pragma unroll
        for (int kq = 0; kq < 4; kq++) {
            float4 a4[8];
#pragma unroll
            for (int i = 0; i < 8; i++)
                a4[i] = *(const float4*)&As[(ty + 8 * i) * 132 + kc * 16 + kq * 4];
#pragma unroll
            for (int kk = 0; kk < 4; kk++) {
                float4 bL = *(const float4*)&Bcur[(kq * 4 + kk) * 256 + 4 * tx];
                float4 bR = *(const float4*)&Bcur[(kq * 4 + kk) * 256 + 128 + 4 * tx];
#pragma unroll
                for (int i = 0; i < 8; i++) {
                    float av = ((const float*)&a4[i])[kk];
                    accL[i].x = fmaf(av, bL.x, accL[i].x);
                    accL[i].y = fmaf(av, bL.y, accL[i].y);
                    accL[i].z = fmaf(av, bL.z, accL[i].z);
                    accL[i].w = fmaf(av, bL.w, accL[i].w);
                    accR[i].x = fmaf(av, bR.x, accR[i].x);
                    accR[i].y = fmaf(av, bR.y, accR[i].y);
                    accR[i].z = fmaf(av, bR.z, accR[i].z);
                    accR[i].w = fmaf(av, bR.w, accR[i].w);
                }
            }
        }
        __syncthreads();   // readers of Bs[kc&1] done; drains kc+1 loads (complete)
    }

    float* Cq = matrix ? kf : qf;
    __half* Cv = matrix ? v2h : v1h;
#pragma unroll
    for (int i = 0; i < 8; i++) {
        int row = mb * 64 + ty + 8 * i;
        *(float4*)(Cq + (size_t)row * 128 + 4 * tx) = accL[i];
        __half2* p = (__half2*)(Cv + (size_t)row * 128 + 4 * tx);
        p[0] = __halves2half2(__float2half(accR[i].x), __float2half(accR[i].y));
        p[1] = __halves2half2(__float2half(accR[i].z), __float2half(accR[i].w));
    }
}

// ---------------- output GEMMs (gll-dbuf, N=128) ----------------------------
__global__ __launch_bounds__(256) void outp_kernel(
        const float* __restrict__ rh, const float* __restrict__ ch,
        const float* __restrict__ Wo1, const float* __restrict__ Wo2,
        float* __restrict__ out) {
    __shared__ float As[64 * 132];
    __shared__ float Bs[2][16 * 128];
    int t = threadIdx.x;
    int matrix = blockIdx.x >> 8;
    int mb = blockIdx.x & 255;
    const float* A  = matrix ? ch : rh;
    const float* Bm = matrix ? Wo2 : Wo1;
    float* C = out + (size_t)matrix * NROW * 128;
    const float* Arow = A + (size_t)mb * 64 * 128;

    int tx = t & 31, ty = t >> 5;
#pragma unroll
    for (int li = 0; li < 8; li++) {
        int idx = li * 256 + t;
        int r = idx >> 5, p = idx & 31;
        *(float4*)&As[r * 132 + 4 * p] = *(const float4*)(Arow + r * 128 + 4 * p);
    }
    // issue B(kc=0): 16 x 128 = 512 float4, 2 per thread, contiguous
#pragma unroll
    for (int li = 0; li < 2; li++) {
        int idx = li * 256 + t;
        GLL(Bm + 4 * idx, &Bs[0][4 * idx]);
    }

    float4 acc4[8];
#pragma unroll
    for (int i = 0; i < 8; i++) acc4[i] = make_float4(0.f, 0.f, 0.f, 0.f);

    __syncthreads();

    for (int kc = 0; kc < 8; kc++) {
        if (kc < 7) {
            const float* src = Bm + (size_t)(kc + 1) * 16 * 128;
            float* dst = Bs[(kc + 1) & 1];
#pragma unroll
            for (int li = 0; li < 2; li++) {
                int idx = li * 256 + t;
                GLL(src + 4 * idx, dst + 4 * idx);
            }
        }
        const float* Bcur = Bs[kc & 1];
#pragma unroll
        for (int kq = 0; kq < 4; kq++) {
            float4 a4[8];
#pragma unroll
            for (int i = 0; i < 8; i++)
                a4[i] = *(const float4*)&As[(ty + 8 * i) * 132 + kc * 16 + kq * 4];
#pragma unroll
            for (int kk = 0; kk < 4; kk++) {
                float4 b4 = *(const float4*)&Bcur[(kq * 4 + kk) * 128 + 4 * tx];
#pragma unroll
                for (int i = 0; i < 8; i++) {
                    float av = ((const float*)&a4[i])[kk];
                    acc4[i].x = fmaf(av, b4.x, acc4[i].x);
                    acc4[i].y = fmaf(av, b4.y, acc4[i].y);
                    acc4[i].z = fmaf(av, b4.z, acc4[i].z);
                    acc4[i].w = fmaf(av, b4.w, acc4[i].w);
                }
            }
        }
        __syncthreads();
    }

#pragma unroll
    for (int i = 0; i < 8; i++) {
        int row = mb * 64 + ty + 8 * i;
        *(float4*)(C + (size_t)row * 128 + 4 * tx) = acc4[i];
    }
}

// ---------------- atomic-free histogram: per-block LDS, u16-packed ----------
__global__ __launch_bounds__(1024) void hist_kernel(
        const int* __restrict__ b_idx, const int* __restrict__ s_idx,
        const int* __restrict__ p_idx, unsigned int* __restrict__ ph) {
    __shared__ unsigned int lh[16384];
    int t = threadIdx.x;
#pragma unroll
    for (int i = 0; i < 16; i++) lh[t + 1024 * i] = 0;
    __syncthreads();
    int base = blockIdx.x * CHUNK;
#pragma unroll
    for (int k = 0; k < 4; k++) {
        int e = base + k * 1024 + t;
        int b = b_idx[e];
        int rbin = (b << 10) + s_idx[e];
        int cbin = 16384 + (b << 10) + p_idx[e];
        atomicAdd(&lh[rbin >> 1], 1u << (16 * (rbin & 1)));
        atomicAdd(&lh[cbin >> 1], 1u << (16 * (cbin & 1)));
    }
    __syncthreads();
    unsigned int* dst = ph + (size_t)blockIdx.x * 16384;
#pragma unroll
    for (int i = 0; i < 16; i++) dst[t + 1024 * i] = lh[t + 1024 * i];
}

// ---- scan1: per-bin serial prefix over the 128 block-partials --------------
__global__ __launch_bounds__(128) void scan1_kernel(
        const unsigned int* __restrict__ ph, int* __restrict__ pbase,
        int* __restrict__ tot) {
    int bin = blockIdx.x * 128 + threadIdx.x;   // 0..32767
    int word = bin >> 1;
    int sh = 16 * (bin & 1);
    int run = 0;
#pragma unroll 8
    for (int j = 0; j < NB; j++) {
        unsigned int v = ph[(size_t)j * 16384 + word];
        pbase[(size_t)j * 32768 + bin] = run;
        run += (v >> sh) & 0xffff;
    }
    tot[bin] = run;
}

// ---- scan2: exclusive scan of 16384 bin totals per side -> offs ------------
__global__ __launch_bounds__(1024) void scan2_kernel(
        const int* __restrict__ tot, int* __restrict__ offs) {
    __shared__ int sdata[1024];
    int side = blockIdx.x;
    int t = threadIdx.x;
    const int* c = tot + side * 16384;
    int* o = offs + side * (16384 + 1);
    int base = t * 16;
    int loc[16];
    int run = 0;
#pragma unroll
    for (int i = 0; i < 16; i++) { loc[i] = run; run += c[base + i]; }
    sdata[t] = run;
    __syncthreads();
    for (int st = 1; st < 1024; st <<= 1) {
        int v = (t >= st) ? sdata[t - st] : 0;
        __syncthreads();
        sdata[t] += v;
        __syncthreads();
    }
    int excl = sdata[t] - run;
#pragma unroll
    for (int i = 0; i < 16; i++) o[base + i] = excl + loc[i];
    if (t == 1023) o[16384] = sdata[1023];
}

// ---- pos: merged col+row positioning (posC+posR of round 9) ----------------
__global__ __launch_bounds__(1024) void pos_kernel(
        const int* __restrict__ b_idx, const int* __restrict__ s_idx,
        const int* __restrict__ p_idx, const float* __restrict__ w,
        const int* __restrict__ pbase, const int* __restrict__ offs,
        int4* __restrict__ ebuf) {
    __shared__ int cur[16384];
    int t = threadIdx.x;
    // phase 1: col cursors
    {
        const int* src = pbase + (size_t)blockIdx.x * 32768 + 16384;
        const int* oc = offs + (16384 + 1);
#pragma unroll
        for (int i = 0; i < 16; i++) {
            int idx = t + 1024 * i;
            cur[idx] = oc[idx] + src[idx];
        }
    }
    __syncthreads();
    int base = blockIdx.x * CHUNK;
    int rowr[4], colr[4], pcr[4];
    float wr[4];
#pragma unroll
    for (int k = 0; k < 4; k++) {
        int e = base + k * 1024 + t;
        int b = b_idx[e];
        rowr[k] = (b << 10) + s_idx[e];
        colr[k] = (b << 10) + p_idx[e];
        wr[k] = w[e];
        pcr[k] = atomicAdd(&cur[colr[k]], 1);
    }
    __syncthreads();
    // phase 2: row cursors
    {
        const int* src = pbase + (size_t)blockIdx.x * 32768;
#pragma unroll
        for (int i = 0; i < 16; i++) {
            int idx = t + 1024 * i;
            cur[idx] = offs[idx] + src[idx];
        }
    }
    __syncthreads();
#pragma unroll
    for (int k = 0; k < 4; k++) {
        int pr = atomicAdd(&cur[rowr[k]], 1);
        ebuf[pr] = make_int4(rowr[k], colr[k], __float_as_int(wr[k]), pcr[k]);
    }
}

// ---------------- fused edge pass (one wave per row, XCD-pinned) ------------
// Round-16: r7 structure restored (r9's 2-deep pipeline spilled: WRITE 98MB).
// Edge is VALU-ISSUE-bound (~44us across 3 structures; VALUBusy 54% = ~24us
// of issue; MLP = 128 of ~170 inst/lane/batch). Fix: packed-fp32 MLP --
// hidden pairs (m, m+16) as ext_vector float2 so clang emits v_pk_fma_f32:
// 16 x (3 pk_fma + pk_max) = 64 packed inst replace 128 scalar. Weight pairs
// staged as sA2=(a,a',b,b') / sC2=(c,c',d,d'). Sum regrouped into two
// partials -- ~1e-7 rel, invisible under fp16 ev (r8's regroup passed).
__global__ __launch_bounds__(256) void edge_kernel(
        const float* __restrict__ qf, const float* __restrict__ kf,
        const int4* __restrict__ ebuf, const int* __restrict__ offs_row,
        const float* __restrict__ msW1, const float* __restrict__ msb1,
        const float* __restrict__ msW2, const float* __restrict__ msb2,
        float* __restrict__ entr, float* __restrict__ entc) {
    __shared__ float4 sA2[8 * 17];   // (a_m, a_m+16, b_m, b_m+16)
    __shared__ float4 sC2[8 * 17];   // (c_m, c_m+16, d_m, d_m+16)
    __shared__ float sB2[8];
    int t = threadIdx.x;
    if (t < 128) {
        int h = t >> 4, m = t & 15;
        sA2[h * 17 + m] = make_float4(msW1[h * 64 + m],      msW1[h * 64 + m + 16],
                                      msW1[h * 64 + 32 + m], msW1[h * 64 + 32 + m + 16]);
        sC2[h * 17 + m] = make_float4(msb1[h * 32 + m],      msb1[h * 32 + m + 16],
                                      msW2[h * 32 + m],      msW2[h * 32 + m + 16]);
    }
    if (t < 8) sB2[t] = msb2[t];
    __syncthreads();

    int x = blockIdx.x & 7;          // XCD slot -> buckets x and x+8
    int ridx = blockIdx.x >> 3;      // 0..NRWB-1
    int wv = t >> 6;                 // wave in block (0..3)
    int lane = t & 63;
    int l = lane & 7;                // lane within 8-lane edge group
    int g = lane >> 3;               // edge group (0..7)

    int rl = ridx * 4 + wv;                                   // 0..2047
    int row = ((x + ((rl >> 10) << 3)) << 10) + (rl & 1023);  // global row id
    int s = offs_row[row];
    int cnt = offs_row[row + 1] - s;

    int hh = 2 * (l & 3) + (l >> 2);
    const float4* wa = &sA2[hh * 17];
    const float4* wc = &sC2[hh * 17];
    float bias2 = sB2[hh];

    // q-row fragments, loaded once per row
    const float4* qp4 = (const float4*)(qf + (size_t)row * 128);
    float4 q0 = qp4[l], q1 = qp4[8 + l], q2 = qp4[16 + l], q3 = qp4[24 + l];

    for (int j0 = 0; j0 < cnt; j0 += 8) {
        int j = j0 + g;
        if (j < cnt) {
            int pos = s + j;
            int4 rec = ebuf[pos];
            int col = rec.y;
            float we = __int_as_float(rec.z);
            int pc = rec.w;

            const float4* kp4 = (const float4*)(kf + (size_t)col * 128);
            float p0, p1, p2, p3;
            {
                float4 k4 = kp4[l];
                p0 = fmaf(q0.x, k4.x, fmaf(q0.y, k4.y, fmaf(q0.z, k4.z, q0.w * k4.w)));
            }
            {
                float4 k4 = kp4[8 + l];
                p1 = fmaf(q1.x, k4.x, fmaf(q1.y, k4.y, fmaf(q1.z, k4.z, q1.w * k4.w)));
            }
            {
                float4 k4 = kp4[16 + l];
                p2 = fmaf(q2.x, k4.x, fmaf(q2.y, k4.y, fmaf(q2.z, k4.z, q2.w * k4.w)));
            }
            {
                float4 k4 = kp4[24 + l];
                p3 = fmaf(q3.x, k4.x, fmaf(q3.y, k4.y, fmaf(q3.z, k4.z, q3.w * k4.w)));
            }
            p0 += __shfl_xor(p0, 1); p0 += __shfl_xor(p0, 2);
            p1 += __shfl_xor(p1, 1); p1 += __shfl_xor(p1, 2);
            p2 += __shfl_xor(p2, 1); p2 += __shfl_xor(p2, 2);
            p3 += __shfl_xor(p3, 1); p3 += __shfl_xor(p3, 2);

            int js = l & 3;
            float dot = js == 0 ? p0 : (js == 1 ? p1 : (js == 2 ? p2 : p3));
            float logit = dot * 0.25f;

            // packed MLP: pairs (m, m+16) -> v_pk_fma_f32
            v2f acc2 = {0.f, 0.f};
            v2f lg2 = {logit, logit};
            v2f we2 = {we, we};
#pragma unroll
            for (int m = 0; m < 16; m++) {
                float4 a = wa[m];
                float4 c = wc[m];
                v2f hid = lg2 * (v2f){a.x, a.y} + we2 * (v2f){a.z, a.w} + (v2f){c.x, c.y};
                hid = __builtin_elementwise_max(hid, (v2f){0.f, 0.f});
                acc2 += hid * (v2f){c.z, c.w};
            }
            float outv = bias2 + (acc2.x + acc2.y);

            // fast tanh+exp: tanh(x) = 1 - 2/(e^{2x}+1); ev = e^{10*tanh}
            float u  = __expf(outv + outv);
            float th = 1.0f - 2.0f * __builtin_amdgcn_rcpf(u + 1.0f);
            float ev = __expf(10.0f * th);
            __half evh = __float2half(ev);

            float* er = entr + (size_t)pos * ESTRIDE;
            float* ec = entc + (size_t)pc * ESTRIDE;
            ((__half*)er)[2 + hh] = evh;
            ((__half*)ec)[2 + hh] = evh;
            if (l == 0) {
                er[0] = __int_as_float(col);
                ec[0] = __int_as_float(row);
            }
        }
    }
}

// ---------------- dual group-softmax combine (XCD-pinned, LDS-staged) -------
__global__ __launch_bounds__(128) void combine_kernel(
        const float* __restrict__ entr, const float* __restrict__ entc,
        const int* __restrict__ offs_row, const int* __restrict__ offs_col,
        const __half* __restrict__ v1h, const __half* __restrict__ v2h,
        float* __restrict__ row_heads, float* __restrict__ col_heads) {
    __shared__ float sE[GCAP * ESTRIDE];
    int x = blockIdx.x & 7;
    int r = blockIdx.x >> 3;
    int which = r >> 10;
    int sidx = r & 1023;
    int b = x + ((which & 1) << 3);
    int gl = (b << 10) + sidx;

    int t = threadIdx.x;
    int h = t >> 4;
    const float* ent; const __half* vals; const int* offs; float* outp;
    if (which < 2) { ent = entr; vals = v2h; offs = offs_row; outp = row_heads; }
    else           { ent = entc; vals = v1h; offs = offs_col; outp = col_heads; }
    int s = offs[gl], e_ = offs[gl + 1];
    int cnt = e_ - s;
    int cap = cnt < GCAP ? cnt : GCAP;

    const float* gsrc = ent + (size_t)s * ESTRIDE;
    for (int i = t; i < cap * ESTRIDE; i += 128) sE[i] = gsrc[i];
    __syncthreads();

    float acc = 0.f, den = 0.f;
#pragma unroll 8
    for (int i = 0; i < cap; i++) {
        const float* en = &sE[i * ESTRIDE];
        int other = __float_as_int(en[0]);
        float ev = __half2float(((const __half*)en)[2 + h]);
        float v = __half2float(vals[(size_t)other * 128 + t]);
        acc = fmaf(ev, v, acc);
        den += ev;
    }
    for (int i = cap; i < cnt; i++) {   // pathological-group fallback
        const float* en = gsrc + (size_t)i * ESTRIDE;
        int other = __float_as_int(en[0]);
        float ev = __half2float(((const __half*)en)[2 + h]);
        float v = __half2float(vals[(size_t)other * 128 + t]);
        acc = fmaf(ev, v, acc);
        den += ev;
    }
    outp[(size_t)gl * 128 + t] = acc / (den + 1e-9f);
}

extern "C" void kernel_launch(void* const* d_in, const int* in_sizes, int n_in,
                              void* d_out, int out_size, void* d_ws, size_t ws_size,
                              hipStream_t stream) {
    const float* x1   = (const float*)d_in[0];
    const float* x2   = (const float*)d_in[1];
    const int* b_idx  = (const int*)d_in[2];
    const int* s_idx  = (const int*)d_in[3];
    const int* p_idx  = (const int*)d_in[4];
    const float* w    = (const float*)d_in[5];
    const float* Wqv1 = (const float*)d_in[6];
    const float* Wkv2 = (const float*)d_in[7];
    const float* Wo1  = (const float*)d_in[8];
    const float* Wo2  = (const float*)d_in[9];
    const float* msW1 = (const float*)d_in[10];
    const float* msb1 = (const float*)d_in[11];
    const float* msW2 = (const float*)d_in[12];
    const float* msb2 = (const float*)d_in[13];
    float* out = (float*)d_out;

    // Workspace (~72 MiB) with aliased scratch (lifetimes disjoint):
    float* qf = (float*)d_ws;                         // 8.39 MB
    float* kf = qf + (size_t)NROW * 128;              // 8.39 MB
    __half* v1h = (__half*)(kf + (size_t)NCOL * 128); // 4.19 MB
    __half* v2h = v1h + (size_t)NROW * 128;           // 4.19 MB
    float* entr = (float*)(v2h + (size_t)NCOL * 128); // 10.49 MB
    float* entc = entr + (size_t)EE * ESTRIDE;        // 10.49 MB
    float* row_heads = entc + (size_t)EE * ESTRIDE;   // 8.39 MB
    float* col_heads = row_heads + (size_t)NROW * 128;// 8.39 MB
    int4* ebuf = (int4*)(col_heads + (size_t)NCOL * 128); // 8.39 MB
    int* offs = (int*)(ebuf + EE);                    // 2*(16384+1) ints
    int* tot  = offs + 2 * (16384 + 1);               // 32768 ints
    // aliases: ph -> entc (dead until edge); pbase -> heads (dead until combine).
    unsigned int* ph = (unsigned int*)entc;           // NB*16384 u32 = 8.39 MB
    int* pbase = (int*)row_heads;                     // NB*32768 int = 16.78 MB

    hist_kernel<<<NB, 1024, 0, stream>>>(b_idx, s_idx, p_idx, ph);
    scan1_kernel<<<256, 128, 0, stream>>>(ph, pbase, tot);
    scan2_kernel<<<2, 1024, 0, stream>>>(tot, offs);
    pos_kernel<<<NB, 1024, 0, stream>>>(b_idx, s_idx, p_idx, w, pbase, offs, ebuf);

    proj_kernel<<<512, 256, 0, stream>>>(x1, x2, Wqv1, Wkv2, qf, kf, v1h, v2h);

    edge_kernel<<<8 * NRWB, 256, 0, stream>>>(
        qf, kf, ebuf, offs, msW1, msb1, msW2, msb2, entr, entc);

    combine_kernel<<<2 * NROW, 128, 0, stream>>>(
        entr, entc, offs, offs + (16384 + 1), v1h, v2h, row_heads, col_heads);

    outp_kernel<<<512, 256, 0, stream>>>(row_heads, col_heads, Wo1, Wo2, out);
}

// Round 12
// 241.618 us; speedup vs baseline: 1.0828x; 1.0386x over previous
//
#include <hip/hip_runtime.h>
#include <hip/hip_fp16.h>
#include <math.h>

#define BB   16
#define SS   1024
#define PP   1024
#define HH   8
#define MSS  32
#define EE   524288
#define NROW (BB*SS)   /* 16384 */
#define NCOL (BB*PP)   /* 16384 */
#define ESTRIDE 5      /* dwords per edge entry: [0]=other id, [1..4]=8 x fp16 ev */
#define NRWB 512       /* row-blocks per XCD slot: 512 blocks x 4 waves = 2048 rows */
#define NB   128       /* hist/pos blocks */
#define CHUNK 4096     /* edges per hist/pos block */
#define GCAP 96        /* staged entries per group in combine (fallback past this) */

// async global->LDS, 16B per lane. LDS dest is wave-uniform base + lane*16,
// which matches our linear idx = li*256 + t layout exactly (m104/m108).
#define GLL(gp, lp) __builtin_amdgcn_global_load_lds( \
    (const __attribute__((address_space(1))) void*)(gp), \
    (__attribute__((address_space(3))) void*)(lp), 16, 0, 0)

// ---------------- projection (merged-ct GEMM, gll-dbuf) ---------------------
// BK=16 double-buffered B staging via global_load_lds (zero staging VGPRs;
// round-6's reg-prefetch spilled). Issue kc+1 loads before kc's compute; the
// per-kc __syncthreads drains vmcnt ~2048cy later, so L2 latency hides under
// compute. Accumulation order unchanged -> bit-identical outputs.
__global__ __launch_bounds__(256, 2) void proj_kernel(
        const float* __restrict__ x1, const float* __restrict__ x2,
        const float* __restrict__ Wqv1, const float* __restrict__ Wkv2,
        float* __restrict__ qf, float* __restrict__ kf,
        __half* __restrict__ v1h, __half* __restrict__ v2h) {
    __shared__ float As[64 * 132];
    __shared__ float Bs[2][16 * 256];
    int t = threadIdx.x;
    int bid = blockIdx.x;
    int matrix = bid >> 8;          // 0: x1@Wqv1, 1: x2@Wkv2
    int mb = bid & 255;
    const float* A  = matrix ? x2 : x1;
    const float* Bm = matrix ? Wkv2 : Wqv1;
    const float* Arow = A + (size_t)mb * 64 * 128;

    int tx = t & 31, ty = t >> 5;
    // stage A-tile (64 x 128) once
#pragma unroll
    for (int li = 0; li < 8; li++) {
        int idx = li * 256 + t;
        int r = idx >> 5, p = idx & 31;
        *(float4*)&As[r * 132 + 4 * p] = *(const float4*)(Arow + r * 128 + 4 * p);
    }
    // issue B(kc=0): 16 rows x 256 cols = 1024 float4, 4 per thread, contiguous
#pragma unroll
    for (int li = 0; li < 4; li++) {
        int idx = li * 256 + t;
        GLL(Bm + 4 * idx, &Bs[0][4 * idx]);
    }

    float4 accL[8], accR[8];
#pragma unroll
    for (int i = 0; i < 8; i++) {
        accL[i] = make_float4(0.f, 0.f, 0.f, 0.f);
        accR[i] = make_float4(0.f, 0.f, 0.f, 0.f);
    }

    __syncthreads();   // drains vmcnt (B0 in LDS) + lgkm (As) + barrier

    for (int kc = 0; kc < 8; kc++) {
        if (kc < 7) {   // issue next B tile -> latency hides under this kc's compute
            const float* src = Bm + (size_t)(kc + 1) * 16 * 256;
            float* dst = Bs[(kc + 1) & 1];
#pragma unroll
            for (int li = 0; li < 4; li++) {
                int idx = li * 256 + t;
                GLL(src + 4 * idx, dst + 4 * idx);
            }
        }
        const float* Bcur = Bs[kc & 1];
#pragma unroll
        for (int kq = 0; kq < 4; kq++) {
            float4 a4[8];
#pragma unroll
            for (int i = 0; i < 8; i++)
                a4[i] = *(const float4*)&As[(ty + 8 * i) * 132 + kc * 16 + kq * 4];
#pragma unroll
            for (int kk = 0; kk < 4; kk++) {
                float4 bL = *(const float4*)&Bcur[(kq * 4 + kk) * 256 + 4 * tx];
                float4 bR = *(const float4*)&Bcur[(kq * 4 + kk) * 256 + 128 + 4 * tx];
#pragma unroll
                for (int i = 0; i < 8; i++) {
                    float av = ((const float*)&a4[i])[kk];
                    accL[i].x = fmaf(av, bL.x, accL[i].x);
                    accL[i].y = fmaf(av, bL.y, accL[i].y);
                    accL[i].z = fmaf(av, bL.z, accL[i].z);
                    accL[i].w = fmaf(av, bL.w, accL[i].w);
                    accR[i].x = fmaf(av, bR.x, accR[i].x);
                    accR[i].y = fmaf(av, bR.y, accR[i].y);
                    accR[i].z = fmaf(av, bR.z, accR[i].z);
                    accR[i].w = fmaf(av, bR.w, accR[i].w);
                }
            }
        }
        __syncthreads();   // readers of Bs[kc&1] done; drains kc+1 loads (complete)
    }

    float* Cq = matrix ? kf : qf;
    __half* Cv = matrix ? v2h : v1h;
#pragma unroll
    for (int i = 0; i < 8; i++) {
        int row = mb * 64 + ty + 8 * i;
        *(float4*)(Cq + (size_t)row * 128 + 4 * tx) = accL[i];
        __half2* p = (__half2*)(Cv + (size_t)row * 128 + 4 * tx);
        p[0] = __halves2half2(__float2half(accR[i].x), __float2half(accR[i].y));
        p[1] = __halves2half2(__float2half(accR[i].z), __float2half(accR[i].w));
    }
}

// ---------------- output GEMMs (gll-dbuf, N=128) ----------------------------
__global__ __launch_bounds__(256) void outp_kernel(
        const float* __restrict__ rh, const float* __restrict__ ch,
        const float* __restrict__ Wo1, const float* __restrict__ Wo2,
        float* __restrict__ out) {
    __shared__ float As[64 * 132];
    __shared__ float Bs[2][16 * 128];
    int t = threadIdx.x;
    int matrix = blockIdx.x >> 8;
    int mb = blockIdx.x & 255;
    const float* A  = matrix ? ch : rh;
    const float* Bm = matrix ? Wo2 : Wo1;
    float* C = out + (size_t)matrix * NROW * 128;
    const float* Arow = A + (size_t)mb * 64 * 128;

    int tx = t & 31, ty = t >> 5;
#pragma unroll
    for (int li = 0; li < 8; li++) {
        int idx = li * 256 + t;
        int r = idx >> 5, p = idx & 31;
        *(float4*)&As[r * 132 + 4 * p] = *(const float4*)(Arow + r * 128 + 4 * p);
    }
    // issue B(kc=0): 16 x 128 = 512 float4, 2 per thread, contiguous
#pragma unroll
    for (int li = 0; li < 2; li++) {
        int idx = li * 256 + t;
        GLL(Bm + 4 * idx, &Bs[0][4 * idx]);
    }

    float4 acc4[8];
#pragma unroll
    for (int i = 0; i < 8; i++) acc4[i] = make_float4(0.f, 0.f, 0.f, 0.f);

    __syncthreads();

    for (int kc = 0; kc < 8; kc++) {
        if (kc < 7) {
            const float* src = Bm + (size_t)(kc + 1) * 16 * 128;
            float* dst = Bs[(kc + 1) & 1];
#pragma unroll
            for (int li = 0; li < 2; li++) {
                int idx = li * 256 + t;
                GLL(src + 4 * idx, dst + 4 * idx);
            }
        }
        const float* Bcur = Bs[kc & 1];
#pragma unroll
        for (int kq = 0; kq < 4; kq++) {
            float4 a4[8];
#pragma unroll
            for (int i = 0; i < 8; i++)
                a4[i] = *(const float4*)&As[(ty + 8 * i) * 132 + kc * 16 + kq * 4];
#pragma unroll
            for (int kk = 0; kk < 4; kk++) {
                float4 b4 = *(const float4*)&Bcur[(kq * 4 + kk) * 128 + 4 * tx];
#pragma unroll
                for (int i = 0; i < 8; i++) {
                    float av = ((const float*)&a4[i])[kk];
                    acc4[i].x = fmaf(av, b4.x, acc4[i].x);
                    acc4[i].y = fmaf(av, b4.y, acc4[i].y);
                    acc4[i].z = fmaf(av, b4.z, acc4[i].z);
                    acc4[i].w = fmaf(av, b4.w, acc4[i].w);
                }
            }
        }
        __syncthreads();
    }

#pragma unroll
    for (int i = 0; i < 8; i++) {
        int row = mb * 64 + ty + 8 * i;
        *(float4*)(C + (size_t)row * 128 + 4 * tx) = acc4[i];
    }
}

// ---------------- atomic-free histogram: per-block LDS, u16-packed ----------
__global__ __launch_bounds__(1024) void hist_kernel(
        const int* __restrict__ b_idx, const int* __restrict__ s_idx,
        const int* __restrict__ p_idx, unsigned int* __restrict__ ph) {
    __shared__ unsigned int lh[16384];
    int t = threadIdx.x;
#pragma unroll
    for (int i = 0; i < 16; i++) lh[t + 1024 * i] = 0;
    __syncthreads();
    int base = blockIdx.x * CHUNK;
#pragma unroll
    for (int k = 0; k < 4; k++) {
        int e = base + k * 1024 + t;
        int b = b_idx[e];
        int rbin = (b << 10) + s_idx[e];
        int cbin = 16384 + (b << 10) + p_idx[e];
        atomicAdd(&lh[rbin >> 1], 1u << (16 * (rbin & 1)));
        atomicAdd(&lh[cbin >> 1], 1u << (16 * (cbin & 1)));
    }
    __syncthreads();
    unsigned int* dst = ph + (size_t)blockIdx.x * 16384;
#pragma unroll
    for (int i = 0; i < 16; i++) dst[t + 1024 * i] = lh[t + 1024 * i];
}

// ---- scan1: per-bin serial prefix over the 128 block-partials --------------
__global__ __launch_bounds__(128) void scan1_kernel(
        const unsigned int* __restrict__ ph, int* __restrict__ pbase,
        int* __restrict__ tot) {
    int bin = blockIdx.x * 128 + threadIdx.x;   // 0..32767
    int word = bin >> 1;
    int sh = 16 * (bin & 1);
    int run = 0;
#pragma unroll 8
    for (int j = 0; j < NB; j++) {
        unsigned int v = ph[(size_t)j * 16384 + word];
        pbase[(size_t)j * 32768 + bin] = run;
        run += (v >> sh) & 0xffff;
    }
    tot[bin] = run;
}

// ---- scan2: exclusive scan of 16384 bin totals per side -> offs ------------
__global__ __launch_bounds__(1024) void scan2_kernel(
        const int* __restrict__ tot, int* __restrict__ offs) {
    __shared__ int sdata[1024];
    int side = blockIdx.x;
    int t = threadIdx.x;
    const int* c = tot + side * 16384;
    int* o = offs + side * (16384 + 1);
    int base = t * 16;
    int loc[16];
    int run = 0;
#pragma unroll
    for (int i = 0; i < 16; i++) { loc[i] = run; run += c[base + i]; }
    sdata[t] = run;
    __syncthreads();
    for (int st = 1; st < 1024; st <<= 1) {
        int v = (t >= st) ? sdata[t - st] : 0;
        __syncthreads();
        sdata[t] += v;
        __syncthreads();
    }
    int excl = sdata[t] - run;
#pragma unroll
    for (int i = 0; i < 16; i++) o[base + i] = excl + loc[i];
    if (t == 1023) o[16384] = sdata[1023];
}

// ---- pos: merged col+row positioning (posC+posR of round 9) ----------------
__global__ __launch_bounds__(1024) void pos_kernel(
        const int* __restrict__ b_idx, const int* __restrict__ s_idx,
        const int* __restrict__ p_idx, const float* __restrict__ w,
        const int* __restrict__ pbase, const int* __restrict__ offs,
        int4* __restrict__ ebuf) {
    __shared__ int cur[16384];
    int t = threadIdx.x;
    // phase 1: col cursors
    {
        const int* src = pbase + (size_t)blockIdx.x * 32768 + 16384;
        const int* oc = offs + (16384 + 1);
#pragma unroll
        for (int i = 0; i < 16; i++) {
            int idx = t + 1024 * i;
            cur[idx] = oc[idx] + src[idx];
        }
    }
    __syncthreads();
    int base = blockIdx.x * CHUNK;
    int rowr[4], colr[4], pcr[4];
    float wr[4];
#pragma unroll
    for (int k = 0; k < 4; k++) {
        int e = base + k * 1024 + t;
        int b = b_idx[e];
        rowr[k] = (b << 10) + s_idx[e];
        colr[k] = (b << 10) + p_idx[e];
        wr[k] = w[e];
        pcr[k] = atomicAdd(&cur[colr[k]], 1);
    }
    __syncthreads();
    // phase 2: row cursors
    {
        const int* src = pbase + (size_t)blockIdx.x * 32768;
#pragma unroll
        for (int i = 0; i < 16; i++) {
            int idx = t + 1024 * i;
            cur[idx] = offs[idx] + src[idx];
        }
    }
    __syncthreads();
#pragma unroll
    for (int k = 0; k < 4; k++) {
        int pr = atomicAdd(&cur[rowr[k]], 1);
        ebuf[pr] = make_int4(rowr[k], colr[k], __float_as_int(wr[k]), pcr[k]);
    }
}

// ---------------- fused edge pass (one wave per row, XCD-pinned) ------------
// Round-7 configuration (best measured total, 241.9us). One wave owns one
// row: q-row loaded ONCE into registers, 8 lane-groups walk the row's edges
// 8-at-a-time. MLP reads wp[m] from LDS (broadcast). Fast tanh+exp via
// native v_exp/v_rcp. Four later variants measured neutral-or-worse:
// shfl-MLP (r8 neutral), 2-deep pipeline (r9 spill +15us), packed v2f MLP
// (r11 +9us total) -- VALU-issue plateau ~44us at this register envelope.
__global__ __launch_bounds__(256) void edge_kernel(
        const float* __restrict__ qf, const float* __restrict__ kf,
        const int4* __restrict__ ebuf, const int* __restrict__ offs_row,
        const float* __restrict__ msW1, const float* __restrict__ msb1,
        const float* __restrict__ msW2, const float* __restrict__ msb2,
        float* __restrict__ entr, float* __restrict__ entc) {
    __shared__ float4 sPk[8 * 33];
    __shared__ float sB2[8];
    int t = threadIdx.x;
    {
        int h = t >> 5, m = t & 31;
        sPk[h * 33 + m] = make_float4(msW1[h * 64 + m], msW1[h * 64 + 32 + m],
                                      msb1[h * 32 + m], msW2[h * 32 + m]);
    }
    if (t < 8) sB2[t] = msb2[t];
    __syncthreads();

    int x = blockIdx.x & 7;          // XCD slot -> buckets x and x+8
    int ridx = blockIdx.x >> 3;      // 0..NRWB-1
    int wv = t >> 6;                 // wave in block (0..3)
    int lane = t & 63;
    int l = lane & 7;                // lane within 8-lane edge group
    int g = lane >> 3;               // edge group (0..7)

    int rl = ridx * 4 + wv;                                   // 0..2047
    int row = ((x + ((rl >> 10) << 3)) << 10) + (rl & 1023);  // global row id
    int s = offs_row[row];
    int cnt = offs_row[row + 1] - s;

    int hh = 2 * (l & 3) + (l >> 2);
    const float4* wp = &sPk[hh * 33];
    float bias2 = sB2[hh];

    // q-row fragments, loaded once per row
    const float4* qp4 = (const float4*)(qf + (size_t)row * 128);
    float4 q0 = qp4[l], q1 = qp4[8 + l], q2 = qp4[16 + l], q3 = qp4[24 + l];

    for (int j0 = 0; j0 < cnt; j0 += 8) {
        int j = j0 + g;
        if (j < cnt) {
            int pos = s + j;
            int4 rec = ebuf[pos];
            int col = rec.y;
            float we = __int_as_float(rec.z);
            int pc = rec.w;

            const float4* kp4 = (const float4*)(kf + (size_t)col * 128);
            float p0, p1, p2, p3;
            {
                float4 k4 = kp4[l];
                p0 = fmaf(q0.x, k4.x, fmaf(q0.y, k4.y, fmaf(q0.z, k4.z, q0.w * k4.w)));
            }
            {
                float4 k4 = kp4[8 + l];
                p1 = fmaf(q1.x, k4.x, fmaf(q1.y, k4.y, fmaf(q1.z, k4.z, q1.w * k4.w)));
            }
            {
                float4 k4 = kp4[16 + l];
                p2 = fmaf(q2.x, k4.x, fmaf(q2.y, k4.y, fmaf(q2.z, k4.z, q2.w * k4.w)));
            }
            {
                float4 k4 = kp4[24 + l];
                p3 = fmaf(q3.x, k4.x, fmaf(q3.y, k4.y, fmaf(q3.z, k4.z, q3.w * k4.w)));
            }
            p0 += __shfl_xor(p0, 1); p0 += __shfl_xor(p0, 2);
            p1 += __shfl_xor(p1, 1); p1 += __shfl_xor(p1, 2);
            p2 += __shfl_xor(p2, 1); p2 += __shfl_xor(p2, 2);
            p3 += __shfl_xor(p3, 1); p3 += __shfl_xor(p3, 2);

            int js = l & 3;
            float dot = js == 0 ? p0 : (js == 1 ? p1 : (js == 2 ? p2 : p3));
            float logit = dot * 0.25f;

            float outv = bias2;
#pragma unroll 4
            for (int m = 0; m < MSS; m++) {
                float4 c = wp[m];
                float hid = fmaf(logit, c.x, fmaf(we, c.y, c.z));
                hid = fmaxf(hid, 0.f);
                outv = fmaf(hid, c.w, outv);
            }
            // fast tanh+exp: tanh(x) = 1 - 2/(e^{2x}+1); ev = e^{10*tanh}
            float u  = __expf(outv + outv);
            float th = 1.0f - 2.0f * __builtin_amdgcn_rcpf(u + 1.0f);
            float ev = __expf(10.0f * th);
            __half evh = __float2half(ev);

            float* er = entr + (size_t)pos * ESTRIDE;
            float* ec = entc + (size_t)pc * ESTRIDE;
            ((__half*)er)[2 + hh] = evh;
            ((__half*)ec)[2 + hh] = evh;
            if (l == 0) {
                er[0] = __int_as_float(col);
                ec[0] = __int_as_float(row);
            }
        }
    }
}

// ---------------- dual group-softmax combine (XCD-pinned, LDS-staged) -------
__global__ __launch_bounds__(128) void combine_kernel(
        const float* __restrict__ entr, const float* __restrict__ entc,
        const int* __restrict__ offs_row, const int* __restrict__ offs_col,
        const __half* __restrict__ v1h, const __half* __restrict__ v2h,
        float* __restrict__ row_heads, float* __restrict__ col_heads) {
    __shared__ float sE[GCAP * ESTRIDE];
    int x = blockIdx.x & 7;
    int r = blockIdx.x >> 3;
    int which = r >> 10;
    int sidx = r & 1023;
    int b = x + ((which & 1) << 3);
    int gl = (b << 10) + sidx;

    int t = threadIdx.x;
    int h = t >> 4;
    const float* ent; const __half* vals; const int* offs; float* outp;
    if (which < 2) { ent = entr; vals = v2h; offs = offs_row; outp = row_heads; }
    else           { ent = entc; vals = v1h; offs = offs_col; outp = col_heads; }
    int s = offs[gl], e_ = offs[gl + 1];
    int cnt = e_ - s;
    int cap = cnt < GCAP ? cnt : GCAP;

    const float* gsrc = ent + (size_t)s * ESTRIDE;
    for (int i = t; i < cap * ESTRIDE; i += 128) sE[i] = gsrc[i];
    __syncthreads();

    float acc = 0.f, den = 0.f;
#pragma unroll 8
    for (int i = 0; i < cap; i++) {
        const float* en = &sE[i * ESTRIDE];
        int other = __float_as_int(en[0]);
        float ev = __half2float(((const __half*)en)[2 + h]);
        float v = __half2float(vals[(size_t)other * 128 + t]);
        acc = fmaf(ev, v, acc);
        den += ev;
    }
    for (int i = cap; i < cnt; i++) {   // pathological-group fallback
        const float* en = gsrc + (size_t)i * ESTRIDE;
        int other = __float_as_int(en[0]);
        float ev = __half2float(((const __half*)en)[2 + h]);
        float v = __half2float(vals[(size_t)other * 128 + t]);
        acc = fmaf(ev, v, acc);
        den += ev;
    }
    outp[(size_t)gl * 128 + t] = acc / (den + 1e-9f);
}

extern "C" void kernel_launch(void* const* d_in, const int* in_sizes, int n_in,
                              void* d_out, int out_size, void* d_ws, size_t ws_size,
                              hipStream_t stream) {
    const float* x1   = (const float*)d_in[0];
    const float* x2   = (const float*)d_in[1];
    const int* b_idx  = (const int*)d_in[2];
    const int* s_idx  = (const int*)d_in[3];
    const int* p_idx  = (const int*)d_in[4];
    const float* w    = (const float*)d_in[5];
    const float* Wqv1 = (const float*)d_in[6];
    const float* Wkv2 = (const float*)d_in[7];
    const float* Wo1  = (const float*)d_in[8];
    const float* Wo2  = (const float*)d_in[9];
    const float* msW1 = (const float*)d_in[10];
    const float* msb1 = (const float*)d_in[11];
    const float* msW2 = (const float*)d_in[12];
    const float* msb2 = (const float*)d_in[13];
    float* out = (float*)d_out;

    // Workspace (~72 MiB) with aliased scratch (lifetimes disjoint):
    float* qf = (float*)d_ws;                         // 8.39 MB
    float* kf = qf + (size_t)NROW * 128;              // 8.39 MB
    __half* v1h = (__half*)(kf + (size_t)NCOL * 128); // 4.19 MB
    __half* v2h = v1h + (size_t)NROW * 128;           // 4.19 MB
    float* entr = (float*)(v2h + (size_t)NCOL * 128); // 10.49 MB
    float* entc = entr + (size_t)EE * ESTRIDE;        // 10.49 MB
    float* row_heads = entc + (size_t)EE * ESTRIDE;   // 8.39 MB
    float* col_heads = row_heads + (size_t)NROW * 128;// 8.39 MB
    int4* ebuf = (int4*)(col_heads + (size_t)NCOL * 128); // 8.39 MB
    int* offs = (int*)(ebuf + EE);                    // 2*(16384+1) ints
    int* tot  = offs + 2 * (16384 + 1);               // 32768 ints
    // aliases: ph -> entc (dead until edge); pbase -> heads (dead until combine).
    unsigned int* ph = (unsigned int*)entc;           // NB*16384 u32 = 8.39 MB
    int* pbase = (int*)row_heads;                     // NB*32768 int = 16.78 MB

    hist_kernel<<<NB, 1024, 0, stream>>>(b_idx, s_idx, p_idx, ph);
    scan1_kernel<<<256, 128, 0, stream>>>(ph, pbase, tot);
    scan2_kernel<<<2, 1024, 0, stream>>>(tot, offs);
    pos_kernel<<<NB, 1024, 0, stream>>>(b_idx, s_idx, p_idx, w, pbase, offs, ebuf);

    proj_kernel<<<512, 256, 0, stream>>>(x1, x2, Wqv1, Wkv2, qf, kf, v1h, v2h);

    edge_kernel<<<8 * NRWB, 256, 0, stream>>>(
        qf, kf, ebuf, offs, msW1, msb1, msW2, msb2, entr, entc);

    combine_kernel<<<2 * NROW, 128, 0, stream>>>(
        entr, entc, offs, offs + (16384 + 1), v1h, v2h, row_heads, col_heads);

    outp_kernel<<<512, 256, 0, stream>>>(row_heads, col_heads, Wo1, Wo2, out);
}